// Round 2
// baseline (735.950 us; speedup 1.0000x reference)
//
#include <hip/hip_runtime.h>
#include <stdint.h>

typedef __bf16 bf16;
typedef __bf16 bf16x4 __attribute__((ext_vector_type(4)));
typedef __bf16 bf16x8 __attribute__((ext_vector_type(8)));
typedef float  f32x4  __attribute__((ext_vector_type(4)));

#define TOKENS 4096
#define HDIM   1024
#define NEXP   16
#define KTOP   4
#define NPAIR  (TOKENS*KTOP)   // 16384

__device__ __forceinline__ void gload16(const void* g, void* l) {
  __builtin_amdgcn_global_load_lds(
      (const __attribute__((address_space(1))) unsigned int*)g,
      (__attribute__((address_space(3))) unsigned int*)l, 16, 0, 0);
}

// ---------------- conversions ----------------

__global__ __launch_bounds__(256) void conv_hidden(const float* __restrict__ in,
                                                   bf16* __restrict__ out) {
  int i = blockIdx.x * 256 + threadIdx.x;            // 4096*1024/4 elements
  float4 v = ((const float4*)in)[i];
  bf16x4 o = { (bf16)v.x, (bf16)v.y, (bf16)v.z, (bf16)v.w };
  ((bf16x4*)out)[i] = o;
}

// transpose-convert weights: src [E][1024][NCOLS] fp32 -> dst [E][NCOLS(rows)][1024] bf16
// ILV: gate/up interleave: act col a -> gate row (a>>5)*64+(a&31), up row +32
template<int NCOLS, bool ILV>
__global__ __launch_bounds__(256) void conv_w(const float* __restrict__ src,
                                              bf16* __restrict__ dst) {
  __shared__ float tile[32][65];
  const int e = blockIdx.z;
  const int n0 = blockIdx.x * 64, k0 = blockIdx.y * 32;
  const float* S = src + (size_t)e * 1024 * NCOLS;
  bf16* D = dst + (size_t)e * NCOLS * 1024;
  int tx = threadIdx.x & 63, ty = threadIdx.x >> 6;     // ty 0..3
#pragma unroll
  for (int j = 0; j < 8; ++j)
    tile[ty*8 + j][tx] = S[(size_t)(k0 + ty*8 + j) * NCOLS + n0 + tx];
  __syncthreads();
  int kx = threadIdx.x & 31, nyb = threadIdx.x >> 5;    // nyb 0..7
#pragma unroll
  for (int j = 0; j < 8; ++j) {
    int nl = nyb*8 + j;          // 0..63
    int n2 = n0 + nl;
    int rp;
    if (ILV) {
      int a = (n2 < 1024) ? n2 : (n2 - 1024);
      rp = (a >> 5) * 64 + (a & 31) + ((n2 < 1024) ? 0 : 32);
    } else {
      rp = n2;
    }
    D[(size_t)rp * 1024 + k0 + kx] = (bf16)tile[kx][nl];
  }
}

// ---------------- router ----------------

__global__ __launch_bounds__(256) void router_k(const float* __restrict__ hs,
                                                const float* __restrict__ rw,
                                                const float* __restrict__ rb,
                                                int* __restrict__ counts,
                                                int* __restrict__ topk_e,
                                                float* __restrict__ topk_w) {
  const int t = blockIdx.x;                 // token
  const float* h = hs + (size_t)t * HDIM;
  const int e = threadIdx.x >> 4, l16 = threadIdx.x & 15;
  const float* w = rw + (size_t)e * HDIM;
  float p = 0.f;
#pragma unroll
  for (int j = 0; j < 16; ++j) {
    int k = l16 * 4 + j * 64;
    float4 hv = *(const float4*)(h + k);
    float4 wv = *(const float4*)(w + k);
    p += hv.x*wv.x + hv.y*wv.y + hv.z*wv.z + hv.w*wv.w;
  }
#pragma unroll
  for (int m = 8; m >= 1; m >>= 1) p += __shfl_xor(p, m, 16);
  __shared__ float logits[NEXP];
  if (l16 == 0) logits[e] = p + rb[e];
  __syncthreads();
  if (threadIdx.x == 0) {
    float mx = logits[0];
    for (int i = 1; i < NEXP; ++i) mx = fmaxf(mx, logits[i]);
    float sc[NEXP]; float s = 0.f;
    for (int i = 0; i < NEXP; ++i) { sc[i] = expf(logits[i] - mx); s += sc[i]; }
    float inv = 1.f / s;
    unsigned used = 0;
    for (int k = 0; k < KTOP; ++k) {
      int bi = -1; float bv = -1e30f;
      for (int i = 0; i < NEXP; ++i)
        if (!((used >> i) & 1) && sc[i] > bv) { bv = sc[i]; bi = i; }
      used |= 1u << bi;
      topk_e[t*KTOP + k] = bi;
      topk_w[t*KTOP + k] = bv * inv;
      atomicAdd(&counts[bi], 1);
    }
  }
}

__global__ void scan_k(const int* __restrict__ counts, int* __restrict__ offsets,
                       int* __restrict__ cursors) {
  if (threadIdx.x == 0) {
    int acc = 0;
    for (int e = 0; e < NEXP; ++e) { offsets[e] = acc; acc += counts[e]; }
    offsets[NEXP] = acc;
  }
  if (threadIdx.x < NEXP) cursors[threadIdx.x] = 0;
}

__global__ __launch_bounds__(256) void assign_k(const int* __restrict__ topk_e,
                                                const int* __restrict__ offsets,
                                                int* __restrict__ cursors,
                                                int* __restrict__ token_pos,
                                                int* __restrict__ pos2tok) {
  int t = blockIdx.x * 256 + threadIdx.x;
  if (t >= TOKENS) return;
#pragma unroll
  for (int k = 0; k < KTOP; ++k) {
    int e = topk_e[t*KTOP + k];
    int pos = offsets[e] + atomicAdd(&cursors[e], 1);
    token_pos[t*KTOP + k] = pos;
    pos2tok[pos] = t;
  }
}

// ---------------- grouped GEMM (m97 structure: 128x128, BK=64, 4 waves) ----------------
// C[M][N] = A[M][1024] @ Bw[N][1024]^T ; bf16 in, fp32 acc.
// GATHER: A rows indirected through pos2tok (GEMM1). ACT: GLU epilogue -> act bf16.

template<bool GATHER, bool ACT>
__global__ __launch_bounds__(256)
void gemm_moe(const bf16* __restrict__ A, const bf16* __restrict__ Bw,
              const int* __restrict__ pos2tok, const int* __restrict__ offsets,
              const float* __restrict__ gu_bias, bf16* __restrict__ Cout, int NB) {
  __shared__ bf16 sm[2 * 128 * 64];     // A tile then B tile, linear [128][64]
  const int e  = blockIdx.y >> 5;
  const int rt = blockIdx.y & 31;
  const int start = offsets[e] + rt * 128;
  const int end   = offsets[e + 1];
  if (start >= end) return;
  int rows_valid = end - start; if (rows_valid > 128) rows_valid = 128;
  const int tN  = blockIdx.x;
  const int tid = threadIdx.x, wid = tid >> 6, lane = tid & 63;

  // staging source pointers (per thread, 4 iterations cover 128 rows each tile)
  const bf16* Asrc[4];
#pragma unroll
  for (int i = 0; i < 4; ++i) {
    int r = i*32 + wid*8 + (lane >> 3);
    long row;
    if (GATHER) {
      int g = start + r; if (g > NPAIR - 1) g = NPAIR - 1;
      row = pos2tok[g];
    } else {
      row = start + r;            // act buffer is padded by 128 rows
    }
    Asrc[i] = A + row * 1024 + (lane & 7) * 8;
  }
  const bf16* Bsrc[4];
#pragma unroll
  for (int i = 0; i < 4; ++i) {
    int r = tN * 128 + i*32 + wid*8 + (lane >> 3);
    Bsrc[i] = Bw + ((long)e * NB + r) * 1024 + (lane & 7) * 8;
  }

  f32x4 zero = {0.f, 0.f, 0.f, 0.f};
  f32x4 acc[4][4];
#pragma unroll
  for (int m = 0; m < 4; ++m)
#pragma unroll
    for (int n = 0; n < 4; ++n) acc[m][n] = zero;

  const int wr = wid >> 1, wc = wid & 1;
  const bf16* Al = sm + ((wr*64 + (lane & 15)) * 64) + (lane >> 4) * 8;
  const bf16* Bl = sm + 128*64 + ((wc*64 + (lane & 15)) * 64) + (lane >> 4) * 8;

  for (int k0 = 0; k0 < 1024; k0 += 64) {
#pragma unroll
    for (int i = 0; i < 4; ++i) {
      gload16(Asrc[i] + k0, (char*)sm + (i*32 + wid*8) * 128);
      gload16(Bsrc[i] + k0, (char*)sm + 16384 + (i*32 + wid*8) * 128);
    }
    __syncthreads();   // drains vmcnt before compute
#pragma unroll
    for (int kk = 0; kk < 2; ++kk) {
      bf16x8 af[4], bfr[4];
#pragma unroll
      for (int m = 0; m < 4; ++m) af[m]  = *(const bf16x8*)(Al + m*16*64 + kk*32);
#pragma unroll
      for (int n = 0; n < 4; ++n) bfr[n] = *(const bf16x8*)(Bl + n*16*64 + kk*32);
#pragma unroll
      for (int m = 0; m < 4; ++m)
#pragma unroll
        for (int n = 0; n < 4; ++n)
          acc[m][n] = __builtin_amdgcn_mfma_f32_16x16x32_bf16(af[m], bfr[n], acc[m][n], 0, 0, 0);
    }
    __syncthreads();   // protect LDS before next stage
  }

  const int c = lane & 15;
  const int rbase = (lane >> 4) * 4;
  if constexpr (ACT) {
    // frags: f=0,1 gate (p=0,1); f=2,3 up. act col a = tN*64 + wc*32 + p*16 + c
#pragma unroll
    for (int p = 0; p < 2; ++p) {
      int a = tN*64 + wc*32 + p*16 + c;
      float bg = gu_bias[e*2048 + a];
      float bu = gu_bias[e*2048 + 1024 + a];
#pragma unroll
      for (int m = 0; m < 4; ++m)
#pragma unroll
        for (int r = 0; r < 4; ++r) {
          int rl = wr*64 + m*16 + rbase + r;
          if (rl < rows_valid) {
            float g = acc[m][p][r] + bg;       g = fminf(g, 7.f);
            float u = acc[m][p + 2][r] + bu;   u = fminf(fmaxf(u, -7.f), 7.f);
            float sig = 1.f / (1.f + __expf(-1.702f * g));
            float av = (u + 1.f) * (g * sig);
            Cout[(long)(start + rl) * 1024 + a] = (bf16)av;
          }
        }
    }
  } else {
#pragma unroll
    for (int n = 0; n < 4; ++n) {
      int col = tN*128 + wc*64 + n*16 + c;
#pragma unroll
      for (int m = 0; m < 4; ++m)
#pragma unroll
        for (int r = 0; r < 4; ++r) {
          int rl = wr*64 + m*16 + rbase + r;
          if (rl < rows_valid)
            Cout[(long)(start + rl) * 1024 + col] = (bf16)acc[m][n][r];
        }
    }
  }
}

// ---------------- combine ----------------

__global__ __launch_bounds__(256) void combine_k(const bf16* __restrict__ pair,
                                                 const float* __restrict__ dn_bias,
                                                 const int* __restrict__ token_pos,
                                                 const int* __restrict__ topk_e,
                                                 const float* __restrict__ topk_w,
                                                 float* __restrict__ out) {
  const int t = blockIdx.x;
  const int cidx = threadIdx.x * 4;
  float4 o = {0.f, 0.f, 0.f, 0.f};
#pragma unroll
  for (int k = 0; k < KTOP; ++k) {
    int pos = token_pos[t*KTOP + k];
    int e   = topk_e[t*KTOP + k];
    float w = topk_w[t*KTOP + k];
    bf16x4 v = *(const bf16x4*)(pair + (long)pos * 1024 + cidx);
    float4 b = *(const float4*)(dn_bias + (size_t)e * 1024 + cidx);
    o.x += w * ((float)v[0] + b.x);
    o.y += w * ((float)v[1] + b.y);
    o.z += w * ((float)v[2] + b.z);
    o.w += w * ((float)v[3] + b.w);
  }
  *(float4*)(out + (long)t * 1024 + cidx) = o;
}

// ---------------- launch ----------------

extern "C" void kernel_launch(void* const* d_in, const int* in_sizes, int n_in,
                              void* d_out, int out_size, void* d_ws, size_t ws_size,
                              hipStream_t stream) {
  const float* hs  = (const float*)d_in[0];   // (2,2048,1024)
  const float* rw  = (const float*)d_in[1];   // (16,1024)
  const float* rb  = (const float*)d_in[2];   // (16,)
  const float* guw = (const float*)d_in[3];   // (16,1024,2048)
  const float* gub = (const float*)d_in[4];   // (16,2048)
  const float* dnw = (const float*)d_in[5];   // (16,1024,1024)
  const float* dnb = (const float*)d_in[6];   // (16,1024)
  float* out = (float*)d_out;

  char* w = (char*)d_ws;
  int*   counts    = (int*)(w);
  int*   offsets   = (int*)(w + 256);
  int*   cursors   = (int*)(w + 512);
  int*   topk_e    = (int*)(w + 1024);
  float* topk_w    = (float*)(w + 1024 + 65536);
  int*   token_pos = (int*)(w + 1024 + 2*65536);
  int*   pos2tok   = (int*)(w + 1024 + 3*65536);
  char*  big = w + 1024 + 4*65536;                      // 263168, 256B aligned
  bf16* gu_wt = (bf16*)(big);                           // 16*2048*1024*2 = 64 MiB
  bf16* dn_wt = (bf16*)(big + 67108864);                // 32 MiB
  bf16* hbf   = (bf16*)(big + 100663296);               // 8 MiB
  bf16* act   = (bf16*)(big + 109051904);               // (16384+128)*1024*2
  bf16* pair  = (bf16*)(big + 142868480);               // (16384+128)*1024*2

  hipMemsetAsync(counts, 0, 256, stream);
  conv_hidden<<<4096, 256, 0, stream>>>(hs, hbf);
  conv_w<2048, true ><<<dim3(32, 32, 16), 256, 0, stream>>>(guw, gu_wt);
  conv_w<1024, false><<<dim3(16, 32, 16), 256, 0, stream>>>(dnw, dn_wt);
  router_k<<<TOKENS, 256, 0, stream>>>(hs, rw, rb, counts, topk_e, topk_w);
  scan_k<<<1, 64, 0, stream>>>(counts, offsets, cursors);
  assign_k<<<TOKENS / 256, 256, 0, stream>>>(topk_e, offsets, cursors, token_pos, pos2tok);
  gemm_moe<true,  true ><<<dim3(16, 512), 256, 0, stream>>>(hbf, gu_wt, pos2tok, offsets, gub, act, 2048);
  gemm_moe<false, false><<<dim3(8, 512), 256, 0, stream>>>(act, dn_wt, pos2tok, offsets, nullptr, pair, 1024);
  combine_k<<<TOKENS, 256, 0, stream>>>(pair, dnb, token_pos, topk_e, topk_w, out);
}

// Round 3
// 525.116 us; speedup vs baseline: 1.4015x; 1.4015x over previous
//
#include <hip/hip_runtime.h>
#include <stdint.h>

typedef __bf16 bf16;
typedef __bf16 bf16x4 __attribute__((ext_vector_type(4)));
typedef __bf16 bf16x8 __attribute__((ext_vector_type(8)));
typedef float  f32x4  __attribute__((ext_vector_type(4)));

#define TOKENS 4096
#define HDIM   1024
#define NEXP   16
#define KTOP   4
#define NPAIR  (TOKENS*KTOP)   // 16384

__device__ __forceinline__ void gload16(const void* g, void* l) {
  __builtin_amdgcn_global_load_lds(
      (const __attribute__((address_space(1))) unsigned int*)g,
      (__attribute__((address_space(3))) unsigned int*)l, 16, 0, 0);
}

// ---------------- conversions ----------------

__global__ __launch_bounds__(256) void conv_hidden(const float* __restrict__ in,
                                                   bf16* __restrict__ out) {
  int i = blockIdx.x * 256 + threadIdx.x;            // 4096*1024/4 elements
  float4 v = ((const float4*)in)[i];
  bf16x4 o = { (bf16)v.x, (bf16)v.y, (bf16)v.z, (bf16)v.w };
  ((bf16x4*)out)[i] = o;
}

// transpose-convert weights: src [E][1024][NCOLS] fp32 -> dst [E][NCOLS(rows)][1024] bf16
// ILV: gate/up interleave: act col a -> gate row (a>>5)*64+(a&31), up row +32
template<int NCOLS, bool ILV>
__global__ __launch_bounds__(256) void conv_w(const float* __restrict__ src,
                                              bf16* __restrict__ dst) {
  __shared__ float tile[32][65];
  const int e = blockIdx.z;
  const int n0 = blockIdx.x * 64, k0 = blockIdx.y * 32;
  const float* S = src + (size_t)e * 1024 * NCOLS;
  bf16* D = dst + (size_t)e * NCOLS * 1024;
  int tx = threadIdx.x & 63, ty = threadIdx.x >> 6;     // ty 0..3
#pragma unroll
  for (int j = 0; j < 8; ++j)
    tile[ty*8 + j][tx] = S[(size_t)(k0 + ty*8 + j) * NCOLS + n0 + tx];
  __syncthreads();
  int kx = threadIdx.x & 31, nyb = threadIdx.x >> 5;    // nyb 0..7
#pragma unroll
  for (int j = 0; j < 8; ++j) {
    int nl = nyb*8 + j;          // 0..63
    int n2 = n0 + nl;
    int rp;
    if (ILV) {
      int a = (n2 < 1024) ? n2 : (n2 - 1024);
      rp = (a >> 5) * 64 + (a & 31) + ((n2 < 1024) ? 0 : 32);
    } else {
      rp = n2;
    }
    D[(size_t)rp * 1024 + k0 + kx] = (bf16)tile[kx][nl];
  }
}

// ---------------- router (no global atomics) ----------------

__global__ __launch_bounds__(256) void router_k(const float* __restrict__ hs,
                                                const float* __restrict__ rw,
                                                const float* __restrict__ rb,
                                                int* __restrict__ topk_e,
                                                float* __restrict__ topk_w) {
  const int t = blockIdx.x;                 // token
  const float* h = hs + (size_t)t * HDIM;
  const int e = threadIdx.x >> 4, l16 = threadIdx.x & 15;
  const float* w = rw + (size_t)e * HDIM;
  float p = 0.f;
#pragma unroll
  for (int j = 0; j < 16; ++j) {
    int k = l16 * 4 + j * 64;
    float4 hv = *(const float4*)(h + k);
    float4 wv = *(const float4*)(w + k);
    p += hv.x*wv.x + hv.y*wv.y + hv.z*wv.z + hv.w*wv.w;
  }
#pragma unroll
  for (int m = 8; m >= 1; m >>= 1) p += __shfl_xor(p, m, 16);
  __shared__ float logits[NEXP];
  if (l16 == 0) logits[e] = p + rb[e];
  __syncthreads();
  if (threadIdx.x == 0) {
    float mx = logits[0];
    for (int i = 1; i < NEXP; ++i) mx = fmaxf(mx, logits[i]);
    float sc[NEXP]; float s = 0.f;
    for (int i = 0; i < NEXP; ++i) { sc[i] = expf(logits[i] - mx); s += sc[i]; }
    float inv = 1.f / s;
    unsigned used = 0;
    for (int k = 0; k < KTOP; ++k) {
      int bi = -1; float bv = -1e30f;
      for (int i = 0; i < NEXP; ++i)
        if (!((used >> i) & 1) && sc[i] > bv) { bv = sc[i]; bi = i; }
      used |= 1u << bi;
      topk_e[t*KTOP + k] = bi;
      topk_w[t*KTOP + k] = bv * inv;
    }
  }
}

// ---------------- single-block assignment: hist + scan + positions, LDS only ----------------

__global__ __launch_bounds__(1024) void assign_all(const int* __restrict__ topk_e,
                                                   int* __restrict__ offsets,
                                                   int* __restrict__ token_pos,
                                                   int* __restrict__ pos2tok) {
  __shared__ int cnt[NEXP];
  __shared__ int off[NEXP + 1];
  __shared__ int cur[NEXP];
  const int tid = threadIdx.x;
  if (tid < NEXP) { cnt[tid] = 0; cur[tid] = 0; }
  __syncthreads();
  int myE[16];
#pragma unroll
  for (int j = 0; j < 16; ++j) {
    int s = tid + j * 1024;
    myE[j] = topk_e[s];
    atomicAdd(&cnt[myE[j]], 1);
  }
  __syncthreads();
  if (tid == 0) {
    int a = 0;
    for (int e2 = 0; e2 < NEXP; ++e2) { off[e2] = a; a += cnt[e2]; }
    off[NEXP] = a;
  }
  __syncthreads();
  if (tid < NEXP + 1) offsets[tid] = off[tid];
#pragma unroll
  for (int j = 0; j < 16; ++j) {
    int s = tid + j * 1024;
    int e2 = myE[j];
    int pos = off[e2] + atomicAdd(&cur[e2], 1);
    token_pos[s] = pos;
    pos2tok[pos] = s >> 2;        // token = slot / KTOP
  }
}

// ---------------- grouped GEMM (m97 structure: 128x128, BK=64, 4 waves) ----------------
// C[M][N] = A[M][1024] @ Bw[N][1024]^T ; bf16 in, fp32 acc.
// GATHER: A rows indirected through pos2tok (GEMM1). ACT: GLU epilogue -> act bf16.

template<bool GATHER, bool ACT>
__global__ __launch_bounds__(256)
void gemm_moe(const bf16* __restrict__ A, const bf16* __restrict__ Bw,
              const int* __restrict__ pos2tok, const int* __restrict__ offsets,
              const float* __restrict__ gu_bias, bf16* __restrict__ Cout, int NB) {
  __shared__ bf16 sm[2 * 128 * 64];     // A tile then B tile, linear [128][64]
  const int e  = blockIdx.y >> 5;
  const int rt = blockIdx.y & 31;
  const int start = offsets[e] + rt * 128;
  const int end   = offsets[e + 1];
  if (start >= end) return;
  int rows_valid = end - start; if (rows_valid > 128) rows_valid = 128;
  const int tN  = blockIdx.x;
  const int tid = threadIdx.x, wid = tid >> 6, lane = tid & 63;

  // staging source pointers (per thread, 4 iterations cover 128 rows each tile)
  const bf16* Asrc[4];
#pragma unroll
  for (int i = 0; i < 4; ++i) {
    int r = i*32 + wid*8 + (lane >> 3);
    long row;
    if (GATHER) {
      int g = start + r; if (g > NPAIR - 1) g = NPAIR - 1;
      row = pos2tok[g];
    } else {
      row = start + r;            // act buffer is padded by 128 rows
    }
    Asrc[i] = A + row * 1024 + (lane & 7) * 8;
  }
  const bf16* Bsrc[4];
#pragma unroll
  for (int i = 0; i < 4; ++i) {
    int r = tN * 128 + i*32 + wid*8 + (lane >> 3);
    Bsrc[i] = Bw + ((long)e * NB + r) * 1024 + (lane & 7) * 8;
  }

  f32x4 zero = {0.f, 0.f, 0.f, 0.f};
  f32x4 acc[4][4];
#pragma unroll
  for (int m = 0; m < 4; ++m)
#pragma unroll
    for (int n = 0; n < 4; ++n) acc[m][n] = zero;

  const int wr = wid >> 1, wc = wid & 1;
  const bf16* Al = sm + ((wr*64 + (lane & 15)) * 64) + (lane >> 4) * 8;
  const bf16* Bl = sm + 128*64 + ((wc*64 + (lane & 15)) * 64) + (lane >> 4) * 8;

  for (int k0 = 0; k0 < 1024; k0 += 64) {
#pragma unroll
    for (int i = 0; i < 4; ++i) {
      gload16(Asrc[i] + k0, (char*)sm + (i*32 + wid*8) * 128);
      gload16(Bsrc[i] + k0, (char*)sm + 16384 + (i*32 + wid*8) * 128);
    }
    __syncthreads();   // drains vmcnt before compute
#pragma unroll
    for (int kk = 0; kk < 2; ++kk) {
      bf16x8 af[4], bfr[4];
#pragma unroll
      for (int m = 0; m < 4; ++m) af[m]  = *(const bf16x8*)(Al + m*16*64 + kk*32);
#pragma unroll
      for (int n = 0; n < 4; ++n) bfr[n] = *(const bf16x8*)(Bl + n*16*64 + kk*32);
#pragma unroll
      for (int m = 0; m < 4; ++m)
#pragma unroll
        for (int n = 0; n < 4; ++n)
          acc[m][n] = __builtin_amdgcn_mfma_f32_16x16x32_bf16(af[m], bfr[n], acc[m][n], 0, 0, 0);
    }
    __syncthreads();   // protect LDS before next stage
  }

  const int c = lane & 15;
  const int rbase = (lane >> 4) * 4;
  if constexpr (ACT) {
    // frags: f=0,1 gate (p=0,1); f=2,3 up. act col a = tN*64 + wc*32 + p*16 + c
#pragma unroll
    for (int p = 0; p < 2; ++p) {
      int a = tN*64 + wc*32 + p*16 + c;
      float bg = gu_bias[e*2048 + a];
      float bu = gu_bias[e*2048 + 1024 + a];
#pragma unroll
      for (int m = 0; m < 4; ++m)
#pragma unroll
        for (int r = 0; r < 4; ++r) {
          int rl = wr*64 + m*16 + rbase + r;
          if (rl < rows_valid) {
            float g = acc[m][p][r] + bg;       g = fminf(g, 7.f);
            float u = acc[m][p + 2][r] + bu;   u = fminf(fmaxf(u, -7.f), 7.f);
            float sig = 1.f / (1.f + __expf(-1.702f * g));
            float av = (u + 1.f) * (g * sig);
            Cout[(long)(start + rl) * 1024 + a] = (bf16)av;
          }
        }
    }
  } else {
#pragma unroll
    for (int n = 0; n < 4; ++n) {
      int col = tN*128 + wc*64 + n*16 + c;
#pragma unroll
      for (int m = 0; m < 4; ++m)
#pragma unroll
        for (int r = 0; r < 4; ++r) {
          int rl = wr*64 + m*16 + rbase + r;
          if (rl < rows_valid)
            Cout[(long)(start + rl) * 1024 + col] = (bf16)acc[m][n][r];
        }
    }
  }
}

// ---------------- combine ----------------

__global__ __launch_bounds__(256) void combine_k(const bf16* __restrict__ pair,
                                                 const float* __restrict__ dn_bias,
                                                 const int* __restrict__ token_pos,
                                                 const int* __restrict__ topk_e,
                                                 const float* __restrict__ topk_w,
                                                 float* __restrict__ out) {
  const int t = blockIdx.x;
  const int cidx = threadIdx.x * 4;
  float4 o = {0.f, 0.f, 0.f, 0.f};
#pragma unroll
  for (int k = 0; k < KTOP; ++k) {
    int pos = token_pos[t*KTOP + k];
    int e   = topk_e[t*KTOP + k];
    float w = topk_w[t*KTOP + k];
    bf16x4 v = *(const bf16x4*)(pair + (long)pos * 1024 + cidx);
    float4 b = *(const float4*)(dn_bias + (size_t)e * 1024 + cidx);
    o.x += w * ((float)v[0] + b.x);
    o.y += w * ((float)v[1] + b.y);
    o.z += w * ((float)v[2] + b.z);
    o.w += w * ((float)v[3] + b.w);
  }
  *(float4*)(out + (long)t * 1024 + cidx) = o;
}

// ---------------- launch ----------------

extern "C" void kernel_launch(void* const* d_in, const int* in_sizes, int n_in,
                              void* d_out, int out_size, void* d_ws, size_t ws_size,
                              hipStream_t stream) {
  const float* hs  = (const float*)d_in[0];   // (2,2048,1024)
  const float* rw  = (const float*)d_in[1];   // (16,1024)
  const float* rb  = (const float*)d_in[2];   // (16,)
  const float* guw = (const float*)d_in[3];   // (16,1024,2048)
  const float* gub = (const float*)d_in[4];   // (16,2048)
  const float* dnw = (const float*)d_in[5];   // (16,1024,1024)
  const float* dnb = (const float*)d_in[6];   // (16,1024)
  float* out = (float*)d_out;

  char* w = (char*)d_ws;
  int*   offsets   = (int*)(w + 256);
  int*   topk_e    = (int*)(w + 1024);
  float* topk_w    = (float*)(w + 1024 + 65536);
  int*   token_pos = (int*)(w + 1024 + 2*65536);
  int*   pos2tok   = (int*)(w + 1024 + 3*65536);
  char*  big = w + 1024 + 4*65536;                      // 263168, 256B aligned
  bf16* gu_wt = (bf16*)(big);                           // 16*2048*1024*2 = 64 MiB
  bf16* dn_wt = (bf16*)(big + 67108864);                // 32 MiB
  bf16* hbf   = (bf16*)(big + 100663296);               // 8 MiB
  bf16* act   = (bf16*)(big + 109051904);               // (16384+128)*1024*2
  bf16* pair  = (bf16*)(big + 142868480);               // (16384+128)*1024*2

  conv_hidden<<<4096, 256, 0, stream>>>(hs, hbf);
  conv_w<2048, true ><<<dim3(32, 32, 16), 256, 0, stream>>>(guw, gu_wt);
  conv_w<1024, false><<<dim3(16, 32, 16), 256, 0, stream>>>(dnw, dn_wt);
  router_k<<<TOKENS, 256, 0, stream>>>(hs, rw, rb, topk_e, topk_w);
  assign_all<<<1, 1024, 0, stream>>>(topk_e, offsets, token_pos, pos2tok);
  gemm_moe<true,  true ><<<dim3(16, 512), 256, 0, stream>>>(hbf, gu_wt, pos2tok, offsets, gub, act, 2048);
  gemm_moe<false, false><<<dim3(8, 512), 256, 0, stream>>>(act, dn_wt, pos2tok, offsets, nullptr, pair, 1024);
  combine_k<<<TOKENS, 256, 0, stream>>>(pair, dnb, token_pos, topk_e, topk_w, out);
}

// Round 4
// 487.628 us; speedup vs baseline: 1.5092x; 1.0769x over previous
//
#include <hip/hip_runtime.h>
#include <stdint.h>

typedef __bf16 bf16;
typedef __bf16 bf16x2 __attribute__((ext_vector_type(2)));
typedef __bf16 bf16x4 __attribute__((ext_vector_type(4)));
typedef __bf16 bf16x8 __attribute__((ext_vector_type(8)));
typedef float  f32x4  __attribute__((ext_vector_type(4)));

#define TOKENS 4096
#define HDIM   1024
#define NEXP   16
#define KTOP   4
#define NPAIR  (TOKENS*KTOP)   // 16384

__device__ __forceinline__ void gload16(const void* g, void* l) {
  __builtin_amdgcn_global_load_lds(
      (const __attribute__((address_space(1))) unsigned int*)g,
      (__attribute__((address_space(3))) unsigned int*)l, 16, 0, 0);
}

// ---------------- conversions ----------------

__global__ __launch_bounds__(256) void conv_hidden(const float* __restrict__ in,
                                                   bf16* __restrict__ out) {
  int i = blockIdx.x * 256 + threadIdx.x;            // 4096*1024/4 elements
  float4 v = ((const float4*)in)[i];
  bf16x4 o = { (bf16)v.x, (bf16)v.y, (bf16)v.z, (bf16)v.w };
  ((bf16x4*)out)[i] = o;
}

// transpose-convert weights: src [E][1024][NCOLS] fp32 -> dst [E][NCOLS(rows)][1024] bf16
// 64x64 blocks; bf16 LDS tile stored [n][k]; paired-bf16 128B-contiguous writes.
// ILV: gate/up interleave: act col a -> gate row (a>>5)*64+(a&31), up row +32
template<int NCOLS, bool ILV>
__global__ __launch_bounds__(256) void conv_w(const float* __restrict__ src,
                                              bf16* __restrict__ dst) {
  __shared__ bf16 tile[64][66];                       // [n][k], pad 66 (even)
  const int e = blockIdx.z;
  const int n0 = blockIdx.x * 64, k0 = blockIdx.y * 64;
  const float* S = src + (size_t)e * 1024 * NCOLS;
  bf16* D = dst + (size_t)e * NCOLS * 1024;
  const int tx = threadIdx.x & 63, ty = threadIdx.x >> 6;   // ty 0..3
#pragma unroll
  for (int j = 0; j < 16; ++j) {
    int kr = ty * 16 + j;
    tile[tx][kr] = (bf16)S[(size_t)(k0 + kr) * NCOLS + n0 + tx];
  }
  __syncthreads();
  const int kh = threadIdx.x & 31, nr = threadIdx.x >> 5;   // nr 0..7
#pragma unroll
  for (int j = 0; j < 8; ++j) {
    int nl = j * 8 + nr;
    int n2 = n0 + nl;
    int rp;
    if (ILV) {
      int a = (n2 < 1024) ? n2 : (n2 - 1024);
      rp = (a >> 5) * 64 + (a & 31) + ((n2 < 1024) ? 0 : 32);
    } else {
      rp = n2;
    }
    bf16x2 v = *(const bf16x2*)&tile[nl][kh * 2];
    *(bf16x2*)&D[(size_t)rp * 1024 + k0 + kh * 2] = v;
  }
}

// ---------------- router (no global atomics) ----------------

__global__ __launch_bounds__(256) void router_k(const float* __restrict__ hs,
                                                const float* __restrict__ rw,
                                                const float* __restrict__ rb,
                                                int* __restrict__ topk_e,
                                                float* __restrict__ topk_w) {
  const int t = blockIdx.x;                 // token
  const float* h = hs + (size_t)t * HDIM;
  const int e = threadIdx.x >> 4, l16 = threadIdx.x & 15;
  const float* w = rw + (size_t)e * HDIM;
  float p = 0.f;
#pragma unroll
  for (int j = 0; j < 16; ++j) {
    int k = l16 * 4 + j * 64;
    float4 hv = *(const float4*)(h + k);
    float4 wv = *(const float4*)(w + k);
    p += hv.x*wv.x + hv.y*wv.y + hv.z*wv.z + hv.w*wv.w;
  }
#pragma unroll
  for (int m = 8; m >= 1; m >>= 1) p += __shfl_xor(p, m, 16);
  __shared__ float logits[NEXP];
  if (l16 == 0) logits[e] = p + rb[e];
  __syncthreads();
  if (threadIdx.x == 0) {
    float mx = logits[0];
    for (int i = 1; i < NEXP; ++i) mx = fmaxf(mx, logits[i]);
    float sc[NEXP]; float s = 0.f;
    for (int i = 0; i < NEXP; ++i) { sc[i] = expf(logits[i] - mx); s += sc[i]; }
    float inv = 1.f / s;
    unsigned used = 0;
    for (int k = 0; k < KTOP; ++k) {
      int bi = -1; float bv = -1e30f;
      for (int i = 0; i < NEXP; ++i)
        if (!((used >> i) & 1) && sc[i] > bv) { bv = sc[i]; bi = i; }
      used |= 1u << bi;
      topk_e[t*KTOP + k] = bi;
      topk_w[t*KTOP + k] = bv * inv;
    }
  }
}

// ---------------- single-block assignment: hist + scan + positions, LDS only ----------------

__global__ __launch_bounds__(1024) void assign_all(const int* __restrict__ topk_e,
                                                   int* __restrict__ offsets,
                                                   int* __restrict__ token_pos,
                                                   int* __restrict__ pos2tok) {
  __shared__ int cnt[NEXP];
  __shared__ int off[NEXP + 1];
  __shared__ int cur[NEXP];
  const int tid = threadIdx.x;
  if (tid < NEXP) { cnt[tid] = 0; cur[tid] = 0; }
  __syncthreads();
  int myE[16];
#pragma unroll
  for (int j = 0; j < 16; ++j) {
    int s = tid + j * 1024;
    myE[j] = topk_e[s];
    atomicAdd(&cnt[myE[j]], 1);
  }
  __syncthreads();
  if (tid == 0) {
    int a = 0;
    for (int e2 = 0; e2 < NEXP; ++e2) { off[e2] = a; a += cnt[e2]; }
    off[NEXP] = a;
  }
  __syncthreads();
  if (tid < NEXP + 1) offsets[tid] = off[tid];
#pragma unroll
  for (int j = 0; j < 16; ++j) {
    int s = tid + j * 1024;
    int e2 = myE[j];
    int pos = off[e2] + atomicAdd(&cur[e2], 1);
    token_pos[s] = pos;
    pos2tok[pos] = s >> 2;        // token = slot / KTOP
  }
}

// ---------------- grouped GEMM: 128x128 tile, BK=64, 4 waves, 2-phase dbuf ----------------
// C[M][N] = A[M][1024] @ Bw[N][1024]^T ; bf16 in, fp32 acc.
// GATHER: A rows indirected through pos2tok (GEMM1). ACT: GLU epilogue -> act bf16.

template<bool GATHER, bool ACT>
__global__ __launch_bounds__(256)
void gemm_moe(const bf16* __restrict__ A, const bf16* __restrict__ Bw,
              const int* __restrict__ pos2tok, const int* __restrict__ offsets,
              const float* __restrict__ gu_bias, bf16* __restrict__ Cout, int NB) {
  __shared__ bf16 sm[2][2 * 128 * 64];  // [buf][A(8192) then B(8192)] elements
  const int e  = blockIdx.y >> 5;
  const int rt = blockIdx.y & 31;
  const int start = offsets[e] + rt * 128;
  const int end   = offsets[e + 1];
  if (start >= end) return;
  int rows_valid = end - start; if (rows_valid > 128) rows_valid = 128;
  const int tN  = blockIdx.x;
  const int tid = threadIdx.x, wid = tid >> 6, lane = tid & 63;

  // staging source pointers (per thread, 4 iterations cover 128 rows each tile)
  const bf16* Asrc[4];
#pragma unroll
  for (int i = 0; i < 4; ++i) {
    int r = i*32 + wid*8 + (lane >> 3);
    long row;
    if (GATHER) {
      int g = start + r; if (g > NPAIR - 1) g = NPAIR - 1;
      row = pos2tok[g];
    } else {
      row = start + r;            // act buffer is padded by 128 rows
    }
    Asrc[i] = A + row * 1024 + (lane & 7) * 8;
  }
  const bf16* Bsrc[4];
#pragma unroll
  for (int i = 0; i < 4; ++i) {
    int r = tN * 128 + i*32 + wid*8 + (lane >> 3);
    Bsrc[i] = Bw + ((long)e * NB + r) * 1024 + (lane & 7) * 8;
  }

  f32x4 zero = {0.f, 0.f, 0.f, 0.f};
  f32x4 acc[4][4];
#pragma unroll
  for (int m = 0; m < 4; ++m)
#pragma unroll
    for (int n = 0; n < 4; ++n) acc[m][n] = zero;

  const int wr = wid >> 1, wc = wid & 1;
  const int aoff = (wr*64 + (lane & 15)) * 64 + (lane >> 4) * 8;
  const int boff = 8192 + (wc*64 + (lane & 15)) * 64 + (lane >> 4) * 8;
  const int stg  = (wid*8 + (lane >> 3)) * 128;       // byte offset of this lane's row

  // prologue: stage tile 0 into buf 0
#pragma unroll
  for (int i = 0; i < 4; ++i) {
    gload16(Asrc[i], (char*)sm + i*32*128 + stg);
    gload16(Bsrc[i], (char*)sm + 16384 + i*32*128 + stg);
  }
  __syncthreads();                       // implicit vmcnt(0) drain -> buf0 ready

#pragma unroll
  for (int t = 0; t < 16; ++t) {
    const int cur = t & 1;
    // issue next tile's stage into the other buffer (before compute)
    if (t < 15) {
      const int k0 = (t + 1) * 64;
      const int nb = (cur ^ 1) * 32768;
#pragma unroll
      for (int i = 0; i < 4; ++i) {
        gload16(Asrc[i] + k0, (char*)sm + nb + i*32*128 + stg);
        gload16(Bsrc[i] + k0, (char*)sm + nb + 16384 + i*32*128 + stg);
      }
    }
    // compute current buffer
    const bf16* base = sm[cur];
#pragma unroll
    for (int kk = 0; kk < 2; ++kk) {
      bf16x8 af[4], bfr[4];
#pragma unroll
      for (int m = 0; m < 4; ++m) af[m]  = *(const bf16x8*)(base + aoff + m*16*64 + kk*32);
#pragma unroll
      for (int n = 0; n < 4; ++n) bfr[n] = *(const bf16x8*)(base + boff + n*16*64 + kk*32);
#pragma unroll
      for (int m = 0; m < 4; ++m)
#pragma unroll
        for (int n = 0; n < 4; ++n)
          acc[m][n] = __builtin_amdgcn_mfma_f32_16x16x32_bf16(af[m], bfr[n], acc[m][n], 0, 0, 0);
    }
    __syncthreads();   // drains vmcnt(0): next buffer staged; all reads of cur done
  }

  const int c = lane & 15;
  const int rbase = (lane >> 4) * 4;
  if constexpr (ACT) {
    // frags: f=0,1 gate (p=0,1); f=2,3 up. act col a = tN*64 + wc*32 + p*16 + c
#pragma unroll
    for (int p = 0; p < 2; ++p) {
      int a = tN*64 + wc*32 + p*16 + c;
      float bg = gu_bias[e*2048 + a];
      float bu = gu_bias[e*2048 + 1024 + a];
#pragma unroll
      for (int m = 0; m < 4; ++m)
#pragma unroll
        for (int r = 0; r < 4; ++r) {
          int rl = wr*64 + m*16 + rbase + r;
          if (rl < rows_valid) {
            float g = acc[m][p][r] + bg;       g = fminf(g, 7.f);
            float u = acc[m][p + 2][r] + bu;   u = fminf(fmaxf(u, -7.f), 7.f);
            float sig = 1.f / (1.f + __expf(-1.702f * g));
            float av = (u + 1.f) * (g * sig);
            Cout[(long)(start + rl) * 1024 + a] = (bf16)av;
          }
        }
    }
  } else {
#pragma unroll
    for (int n = 0; n < 4; ++n) {
      int col = tN*128 + wc*64 + n*16 + c;
#pragma unroll
      for (int m = 0; m < 4; ++m)
#pragma unroll
        for (int r = 0; r < 4; ++r) {
          int rl = wr*64 + m*16 + rbase + r;
          if (rl < rows_valid)
            Cout[(long)(start + rl) * 1024 + col] = (bf16)acc[m][n][r];
        }
    }
  }
}

// ---------------- combine ----------------

__global__ __launch_bounds__(256) void combine_k(const bf16* __restrict__ pair,
                                                 const float* __restrict__ dn_bias,
                                                 const int* __restrict__ token_pos,
                                                 const int* __restrict__ topk_e,
                                                 const float* __restrict__ topk_w,
                                                 float* __restrict__ out) {
  const int t = blockIdx.x;
  const int cidx = threadIdx.x * 4;
  float4 o = {0.f, 0.f, 0.f, 0.f};
#pragma unroll
  for (int k = 0; k < KTOP; ++k) {
    int pos = token_pos[t*KTOP + k];
    int e   = topk_e[t*KTOP + k];
    float w = topk_w[t*KTOP + k];
    bf16x4 v = *(const bf16x4*)(pair + (long)pos * 1024 + cidx);
    float4 b = *(const float4*)(dn_bias + (size_t)e * 1024 + cidx);
    o.x += w * ((float)v[0] + b.x);
    o.y += w * ((float)v[1] + b.y);
    o.z += w * ((float)v[2] + b.z);
    o.w += w * ((float)v[3] + b.w);
  }
  *(float4*)(out + (long)t * 1024 + cidx) = o;
}

// ---------------- launch ----------------

extern "C" void kernel_launch(void* const* d_in, const int* in_sizes, int n_in,
                              void* d_out, int out_size, void* d_ws, size_t ws_size,
                              hipStream_t stream) {
  const float* hs  = (const float*)d_in[0];   // (2,2048,1024)
  const float* rw  = (const float*)d_in[1];   // (16,1024)
  const float* rb  = (const float*)d_in[2];   // (16,)
  const float* guw = (const float*)d_in[3];   // (16,1024,2048)
  const float* gub = (const float*)d_in[4];   // (16,2048)
  const float* dnw = (const float*)d_in[5];   // (16,1024,1024)
  const float* dnb = (const float*)d_in[6];   // (16,1024)
  float* out = (float*)d_out;

  char* w = (char*)d_ws;
  int*   offsets   = (int*)(w + 256);
  int*   topk_e    = (int*)(w + 1024);
  float* topk_w    = (float*)(w + 1024 + 65536);
  int*   token_pos = (int*)(w + 1024 + 2*65536);
  int*   pos2tok   = (int*)(w + 1024 + 3*65536);
  char*  big = w + 1024 + 4*65536;                      // 263168, 256B aligned
  bf16* gu_wt = (bf16*)(big);                           // 16*2048*1024*2 = 64 MiB
  bf16* dn_wt = (bf16*)(big + 67108864);                // 32 MiB
  bf16* hbf   = (bf16*)(big + 100663296);               // 8 MiB
  bf16* act   = (bf16*)(big + 109051904);               // (16384+128)*1024*2
  bf16* pair  = (bf16*)(big + 142868480);               // (16384+128)*1024*2

  conv_hidden<<<4096, 256, 0, stream>>>(hs, hbf);
  conv_w<2048, true ><<<dim3(32, 16, 16), 256, 0, stream>>>(guw, gu_wt);
  conv_w<1024, false><<<dim3(16, 16, 16), 256, 0, stream>>>(dnw, dn_wt);
  router_k<<<TOKENS, 256, 0, stream>>>(hs, rw, rb, topk_e, topk_w);
  assign_all<<<1, 1024, 0, stream>>>(topk_e, offsets, token_pos, pos2tok);
  gemm_moe<true,  true ><<<dim3(16, 512), 256, 0, stream>>>(hbf, gu_wt, pos2tok, offsets, gub, act, 2048);
  gemm_moe<false, false><<<dim3(8, 512), 256, 0, stream>>>(act, dn_wt, pos2tok, offsets, nullptr, pair, 1024);
  combine_k<<<TOKENS, 256, 0, stream>>>(pair, dnb, token_pos, topk_e, topk_w, out);
}